// Round 5
// baseline (1713.808 us; speedup 1.0000x reference)
//
#include <hip/hip_runtime.h>
#include <stdint.h>

#define H_    2048
#define B_    128
#define T_    64
#define E_    300
#define NKU   76        // K units of 32: 64 for h (2048) + 12 for x (384 padded)
#define XGRP  48        // 384/8 x-groups per timestep
#define NWG   256
#define NTHR  512

typedef unsigned short u16;
typedef uint32_t u32;
typedef short bf8 __attribute__((ext_vector_type(8)));
typedef float f4 __attribute__((ext_vector_type(4)));

__device__ __forceinline__ u16 f2b(float f) {
    u32 u = __float_as_uint(f);
    u += 0x7fffu + ((u >> 16) & 1u);   // round-to-nearest-even
    return (u16)(u >> 16);
}
__device__ __forceinline__ float sigm(float x) { return 1.f / (1.f + __expf(-x)); }
__device__ __forceinline__ float tanh_(float x) {
    float xx = fminf(fmaxf(x, -15.f), 15.f);
    float e = __expf(2.f * xx);
    return (e - 1.f) / (e + 1.f);
}

// ---- prep: pack weights into per-wave MFMA fragment order (n=32 per WG), ----
// frag id f = ((wg*76 + ku)*2 + nt)*64 + lane ; 8 u16/lane.
// element: nl = nt*16 + (lane&15) -> g = nl&3 (gate-minor), jj = nl>>2 (0..7);
//          k = ku*32 + (lane>>4)*8 + j ; w-row = g*H + wg*8 + jj.
__global__ void prep_kernel(const float* __restrict__ w_hh, const float* __restrict__ w_ih,
                            const float* __restrict__ b_ih, const float* __restrict__ b_hh,
                            u16* __restrict__ wP, float* __restrict__ bsP,
                            u16* __restrict__ hP0, unsigned* __restrict__ bar) {
    int tid = blockIdx.x * blockDim.x + threadIdx.x;
    int np = gridDim.x * blockDim.x;
    const int NF = NWG * NKU * 2 * 64;
    for (int f = tid; f < NF; f += np) {
        int lane = f & 63;
        int fr = f >> 6;
        int nt = fr & 1;
        int rest = fr >> 1;
        int ku = rest % NKU;
        int wg = rest / NKU;
        int l15 = lane & 15, q = lane >> 4;
        int nl = nt * 16 + l15;
        int g = nl & 3, jj = nl >> 2;
        int ng = g * H_ + wg * 8 + jj;
        int k0 = ku * 32 + q * 8;
        union { u16 s[8]; uint4 v; } tmp;
#pragma unroll
        for (int j = 0; j < 8; ++j) {
            int k = k0 + j;
            float v;
            if (k < H_) v = w_hh[(size_t)ng * H_ + k];
            else { int kx = k - H_; v = (kx < E_) ? w_ih[(size_t)ng * E_ + kx] : 0.f; }
            tmp.s[j] = f2b(v);
        }
        *(uint4*)&wP[(size_t)f * 8] = tmp.v;
    }
    // packed bias: bsP[wg*32 + jj*4 + g]
    for (int n = tid; n < NWG * 32; n += np) {
        int wg = n >> 5, nl = n & 31;
        int jj = nl >> 2, g = nl & 3;
        int src = g * H_ + wg * 8 + jj;
        bsP[n] = b_ih[src] + b_hh[src];
    }
    // zero h0 (packed [kg][m][8] bf16) and barrier counters
    for (int i = tid; i < (H_ / 8) * B_ * 8 / 2; i += np) ((u32*)hP0)[i] = 0u;
    for (int i = tid; i < 144; i += np) bar[i] = 0u;
}

// ---- embedding gather -> packed bf16 xP[t][gx][b][8] ----
__global__ void gather_kernel(const int* __restrict__ input, const float* __restrict__ embed,
                              u16* __restrict__ xP) {
    int t = blockIdx.x;
    u16* xt = xP + (size_t)t * XGRP * B_ * 8;
    for (int id = threadIdx.x; id < XGRP * B_; id += blockDim.x) {
        int b = id & (B_ - 1);
        int gx = id >> 7;
        int row = input[b * T_ + t];
        const float* src = embed + (size_t)row * E_;
        union { u16 s[8]; uint4 v; } tmp;
#pragma unroll
        for (int j = 0; j < 8; ++j) {
            int k = gx * 8 + j;
            tmp.s[j] = (k < E_) ? f2b(src[k]) : (u16)0;
        }
        *(uint4*)&xt[(size_t)id * 8] = tmp.v;   // id = gx*128 + b
    }
}

// ---- persistent weight-stationary LSTM: 256 WGs x 512 thr, all 64 steps ----
// WG = 8 hidden cols x 4 gates (n=32) x all 128 m. Wave wid: contiguous K-slice
// (10 or 9 ku of 32) held STATIONARY in VGPRs (Wf). K-loop: packed h/x frags
// global->VGPR double-buffered, 8 loads : 16 MFMA per ku, no LDS, no barriers.
// Epilogue: 8-way cross-wave LDS reduce (4 m-phases) + fused cell, c in LDS.
// Grid sync: h stores drained by __syncthreads; one threadfence(wbl2) + one
// acquire(buffer_inv) per CU per step; 8 spread group counters -> 1 root.
__global__ __launch_bounds__(NTHR, 2) void
lstm_persist(const u16* __restrict__ xb, const u16* __restrict__ wP,
             const float* __restrict__ bsP, u16* __restrict__ h0,
             u16* __restrict__ h1, unsigned* __restrict__ bar,
             float* __restrict__ outp) {
    __shared__ float bufs[8][32][36];   // [wave][m-local 32][n 32 + 4 pad] = 36 KB
    __shared__ float cst[B_][8];        // c-state [m][jj] = 4 KB
    int tid = threadIdx.x;
    int wid = tid >> 6, lane = tid & 63;
    int l15 = lane & 15, q = lane >> 4;
    int wg = blockIdx.x;

    int cnt = (wid < 4) ? 10 : 9;
    int ks  = (wid < 4) ? wid * 10 : 40 + (wid - 4) * 9;

    // stationary weight fragments: Wf[i][nt], ku = ks+i
    bf8 Wf[10][2];
#pragma unroll
    for (int i = 0; i < 10; ++i)
        if (i < cnt) {
            const u16* wb = wP + ((size_t)(wg * NKU + ks + i) * 2) * 512 + lane * 8;
            Wf[i][0] = *(const bf8*)wb;
            Wf[i][1] = *(const bf8*)(wb + 512);
        }

    int hoff = q * 1024 + l15 * 8;

    // cell threads: tid<128, 2 adjacent jj each
    int cjj0 = (tid & 3) * 2, cml = (tid >> 2) & 31;
    f4 bv0 = {0,0,0,0}, bv1 = {0,0,0,0};
    if (tid < 128) {
        bv0 = *(const f4*)&bsP[wg * 32 + cjj0 * 4];
        bv1 = *(const f4*)&bsP[wg * 32 + cjj0 * 4 + 4];
    }
    for (int i = tid; i < B_ * 8; i += NTHR) ((float*)cst)[i] = 0.f;

    for (int t = 0; t < T_; ++t) {
        const u16* hin = (t & 1) ? h1 : h0;
        u16* hout      = (t & 1) ? h0 : h1;
        const u16* xt = xb + (size_t)t * (XGRP * B_ * 8);

        f4 acc[2][8];
#pragma unroll
        for (int nt = 0; nt < 2; ++nt)
#pragma unroll
            for (int mt = 0; mt < 8; ++mt) acc[nt][mt] = (f4)0.f;

#define LDH(KU, HB_) do {                                                     \
        int ku_ = (KU);                                                       \
        const u16* hb_ = ((ku_ < 64) ? (hin + (size_t)ku_ * 4096)             \
                                     : (xt + (size_t)(ku_ - 64) * 4096)) + hoff; \
        _Pragma("unroll")                                                     \
        for (int mt_ = 0; mt_ < 8; ++mt_) HB_[mt_] = *(const bf8*)(hb_ + mt_ * 128); \
    } while (0)

#define MM2(WI, HB_) do {                                                     \
        _Pragma("unroll")                                                     \
        for (int mt_ = 0; mt_ < 8; ++mt_) {                                   \
            acc[0][mt_] = __builtin_amdgcn_mfma_f32_16x16x32_bf16(Wf[WI][0], HB_[mt_], acc[0][mt_], 0, 0, 0); \
            acc[1][mt_] = __builtin_amdgcn_mfma_f32_16x16x32_bf16(Wf[WI][1], HB_[mt_], acc[1][mt_], 0, 0, 0); \
        }                                                                     \
    } while (0)

        bf8 hA[8], hB[8];
        LDH(ks, hA);
#pragma unroll
        for (int i = 0; i < 10; i += 2) {
            if (i >= cnt) break;
            if (i + 1 < cnt) LDH(ks + i + 1, hB);
            MM2(i, hA);
            if (i + 1 >= cnt) break;
            if (i + 2 < cnt) LDH(ks + i + 2, hA);
            MM2(i + 1, hB);
        }
#undef LDH
#undef MM2

        // ---- epilogue: 4 m-phases of write partials -> 8-way reduce -> cell ----
        bool last = (t == T_ - 1);
#pragma unroll
        for (int p = 0; p < 4; ++p) {
            __syncthreads();
#pragma unroll
            for (int mh = 0; mh < 2; ++mh) {
                int mt = p * 2 + mh;
                // D layout: col(l15) = m-local-in-16, row(q*4+r) = n-local-in-nt
                *(f4*)&bufs[wid][mh * 16 + l15][q * 4]      = acc[0][mt];
                *(f4*)&bufs[wid][mh * 16 + l15][16 + q * 4] = acc[1][mt];
            }
            __syncthreads();
            if (tid < 128) {
                int m = p * 32 + cml;
                f4 s0 = {0,0,0,0}, s1 = {0,0,0,0};
#pragma unroll
                for (int w = 0; w < 8; ++w) {
                    f4 v0 = *(const f4*)&bufs[w][cml][cjj0 * 4];
                    f4 v1 = *(const f4*)&bufs[w][cml][cjj0 * 4 + 4];
                    s0[0] += v0[0]; s0[1] += v0[1]; s0[2] += v0[2]; s0[3] += v0[3];
                    s1[0] += v1[0]; s1[1] += v1[1]; s1[2] += v1[2]; s1[3] += v1[3];
                }
                float i0 = sigm(s0[0] + bv0[0]), f0 = sigm(s0[1] + bv0[1]);
                float g0 = tanh_(s0[2] + bv0[2]), o0 = sigm(s0[3] + bv0[3]);
                float i1 = sigm(s1[0] + bv1[0]), f1 = sigm(s1[1] + bv1[1]);
                float g1 = tanh_(s1[2] + bv1[2]), o1 = sigm(s1[3] + bv1[3]);
                float c0 = f0 * cst[m][cjj0] + i0 * g0;
                float c1 = f1 * cst[m][cjj0 + 1] + i1 * g1;
                cst[m][cjj0] = c0;
                cst[m][cjj0 + 1] = c1;
                float hn0 = o0 * tanh_(c0);
                float hn1 = o1 * tanh_(c1);
                // packed h store: one u32 (two bf16), group kg == wg
                ((u32*)hout)[wg * 512 + m * 4 + (cjj0 >> 1)] =
                    (u32)f2b(hn0) | ((u32)f2b(hn1) << 16);
                if (last) {
                    float2 ov = {hn0, hn1};
                    *(float2*)&outp[(size_t)m * H_ + wg * 8 + cjj0] = ov;
                }
            }
        }

        // ---- grid barrier: group counters (8 lines) -> root; 1 fence+inv per CU ----
        if (t < T_ - 1) {
            __syncthreads();            // drains vmcnt: all h stores complete in L2
            if (tid == 0) {
                __threadfence();        // wbl2: flush this XCD's dirty h lines to L3
                unsigned old = __hip_atomic_fetch_add(&bar[(wg & 7) * 16], 1u,
                                   __ATOMIC_RELAXED, __HIP_MEMORY_SCOPE_AGENT);
                if (old == 32u * (unsigned)(t + 1) - 1u)
                    __hip_atomic_fetch_add(&bar[128], 1u,
                        __ATOMIC_RELAXED, __HIP_MEMORY_SCOPE_AGENT);
                unsigned tgt = 8u * (unsigned)(t + 1);
                while (__hip_atomic_load(&bar[128], __ATOMIC_RELAXED,
                                         __HIP_MEMORY_SCOPE_AGENT) < tgt)
                    __builtin_amdgcn_s_sleep(1);
                (void)__hip_atomic_load(&bar[128], __ATOMIC_ACQUIRE,
                                        __HIP_MEMORY_SCOPE_AGENT);  // buffer_inv
            }
            __syncthreads();
        }
    }
}

extern "C" void kernel_launch(void* const* d_in, const int* in_sizes, int n_in,
                              void* d_out, int out_size, void* d_ws, size_t ws_size,
                              hipStream_t stream) {
    const int*   input = (const int*)d_in[0];
    const float* embed = (const float*)d_in[1];
    const float* w_ih  = (const float*)d_in[2];
    const float* w_hh  = (const float*)d_in[3];
    const float* b_ih  = (const float*)d_in[4];
    const float* b_hh  = (const float*)d_in[5];
    float* out = (float*)d_out;

    char* ws = (char*)d_ws;
    size_t o = 0;
    u16* wP   = (u16*)(ws + o); o += (size_t)NWG * NKU * 2 * 512 * 2;     // 39.85 MB
    u16* xP   = (u16*)(ws + o); o += (size_t)T_ * XGRP * B_ * 8 * 2;      // 6.29 MB
    u16* hP0  = (u16*)(ws + o); o += (size_t)(H_ / 8) * B_ * 8 * 2;       // 512 KB
    u16* hP1  = (u16*)(ws + o); o += (size_t)(H_ / 8) * B_ * 8 * 2;       // 512 KB
    float* bsP = (float*)(ws + o); o += (size_t)NWG * 32 * 4;             // 32 KB
    o = (o + 255) & ~(size_t)255;
    unsigned* bar = (unsigned*)(ws + o); o += 144 * 4;

    prep_kernel<<<2048, 256, 0, stream>>>(w_hh, w_ih, b_ih, b_hh, wP, bsP, hP0, bar);
    gather_kernel<<<T_, 256, 0, stream>>>(input, embed, xP);

    void* kargs[] = {(void*)&xP, (void*)&wP, (void*)&bsP,
                     (void*)&hP0, (void*)&hP1, (void*)&bar, (void*)&out};
    hipLaunchCooperativeKernel((void*)lstm_persist, dim3(NWG), dim3(NTHR),
                               kargs, 0, stream);
}